// Round 1
// baseline (1123.026 us; speedup 1.0000x reference)
//
#include <hip/hip_runtime.h>

#define GH 64   // GRU hidden
#define LS 32   // window length (L_S == L_F)
#define HF 32   // fast hidden H
#define DS 16   // hop (D_S == D_F)

__device__ __forceinline__ float sigmf(float v)     { return 1.0f / (1.0f + __expf(-v)); }
__device__ __forceinline__ float tanhfastf(float v) { return 1.0f - 2.0f / (__expf(2.0f * v) + 1.0f); }

// Block = 256 threads = (kq: 4 waves) x (g: 64 lanes). Block owns 4 sequences.
// Thread (kq,g) holds weights W[k][j] for k in [kq*16, kq*16+16), j in {g, g+64, g+128}
// for BOTH Wih and Whh in registers (96 floats), reused across 4 seqs x 32 steps.
// Per step: partial dot-products -> LDS reduce across kq -> wave0 computes gates.
// hseq is updated IN PLACE (step t reads prev-layer h[t] before overwriting with
// this layer's relu(h_t)), so one 32KB buffer serves all 4 layers.
__global__ __launch_bounds__(256, 3) void slow_gru_kernel(
    const float* __restrict__ x,
    const float* __restrict__ siW,  const float* __restrict__ sib,
    const float* __restrict__ Wih,  const float* __restrict__ Whh,
    const float* __restrict__ bih,  const float* __restrict__ bhh,
    const float* __restrict__ soW,  const float* __restrict__ sob,
    const float* __restrict__ s2sW, const float* __restrict__ s2sb,
    float* __restrict__ Abuf, float* __restrict__ Gbuf,
    int T, int ns, int BS)
{
    __shared__ float hseq[4][LS][GH];   // 32 KB: per-seq per-t activations (in-place across layers)
    __shared__ float red[4][6][GH];     // 6 KB: cross-wave partial sums
    __shared__ float hstate[GH];        // pre-relu recurrent state (one seq at a time)
    __shared__ float sfb[4][GH];        // slow_feat staging

    const int tid = threadIdx.x;
    const int g   = tid & 63;
    const int kq  = tid >> 6;

    int seqs[4];
    #pragma unroll
    for (int s = 0; s < 4; ++s) {
        int q = blockIdx.x * 4 + s;
        seqs[s] = q < BS ? q : (BS - 1);   // duplicates write identical values -> benign
    }

    // layer-0 input: h0 = relu(x_t * siW + sib)
    for (int idx = tid; idx < 4 * LS * GH; idx += 256) {
        int s  = idx >> 11;
        int t  = (idx >> 6) & 31;
        int gg = idx & 63;
        int q  = seqs[s];
        int b  = q / ns, si = q - b * ns;
        float xv = x[b * T + si * DS + t];
        float h0 = xv * siW[gg] + sib[gg];
        hseq[s][t][gg] = h0 > 0.0f ? h0 : 0.0f;
    }
    __syncthreads();

    for (int l = 0; l < 4; ++l) {
        // ---- stage this layer's weight slice into registers ----
        float wih[16][3], whh[16][3];
        const float* Wl  = Wih + (size_t)l * GH * 3 * GH;
        const float* Wl2 = Whh + (size_t)l * GH * 3 * GH;
        #pragma unroll
        for (int i = 0; i < 16; ++i) {
            int k = kq * 16 + i;
            #pragma unroll
            for (int c = 0; c < 3; ++c) {
                wih[i][c] = Wl [k * 192 + c * 64 + g];
                whh[i][c] = Wl2[k * 192 + c * 64 + g];
            }
        }
        float bi[3], bh[3];
        #pragma unroll
        for (int c = 0; c < 3; ++c) {
            bi[c] = bih[l * 192 + c * 64 + g];
            bh[c] = bhh[l * 192 + c * 64 + g];
        }

        for (int s = 0; s < 4; ++s) {
            if (tid < GH) hstate[tid] = 0.0f;
            __syncthreads();
            for (int t = 0; t < LS; ++t) {
                // fused K=128 projection: ih-part from prev-layer h (hseq, still
                // un-overwritten at index t) + hh-part from recurrent state.
                const float4* hs4 = reinterpret_cast<const float4*>(hseq[s][t]);
                const float4* hc4 = reinterpret_cast<const float4*>(hstate);
                float a0 = 0, a1 = 0, a2 = 0, r0 = 0, r1 = 0, r2 = 0;
                #pragma unroll
                for (int i4 = 0; i4 < 4; ++i4) {
                    float4 hi = hs4[kq * 4 + i4];     // LDS broadcast (uniform addr per wave)
                    float4 hc = hc4[kq * 4 + i4];
                    float he[4] = {hi.x, hi.y, hi.z, hi.w};
                    float ce[4] = {hc.x, hc.y, hc.z, hc.w};
                    #pragma unroll
                    for (int e = 0; e < 4; ++e) {
                        int i = i4 * 4 + e;
                        a0 += he[e] * wih[i][0]; a1 += he[e] * wih[i][1]; a2 += he[e] * wih[i][2];
                        r0 += ce[e] * whh[i][0]; r1 += ce[e] * whh[i][1]; r2 += ce[e] * whh[i][2];
                    }
                }
                red[kq][0][g] = a0; red[kq][1][g] = a1; red[kq][2][g] = a2;
                red[kq][3][g] = r0; red[kq][4][g] = r1; red[kq][5][g] = r2;
                __syncthreads();
                if (tid < GH) {   // wave 0 computes the gates for all 64 channels
                    float s0 = red[0][0][g] + red[1][0][g] + red[2][0][g] + red[3][0][g] + bi[0];
                    float s1 = red[0][1][g] + red[1][1][g] + red[2][1][g] + red[3][1][g] + bi[1];
                    float s2 = red[0][2][g] + red[1][2][g] + red[2][2][g] + red[3][2][g] + bi[2];
                    float h0 = red[0][3][g] + red[1][3][g] + red[2][3][g] + red[3][3][g] + bh[0];
                    float h1 = red[0][4][g] + red[1][4][g] + red[2][4][g] + red[3][4][g] + bh[1];
                    float h2 = red[0][5][g] + red[1][5][g] + red[2][5][g] + red[3][5][g] + bh[2];
                    float r  = sigmf(s0 + h0);
                    float z  = sigmf(s1 + h1);
                    float nn = tanhfastf(s2 + r * h2);   // bhh_n correctly inside r*hg_n
                    float hp = hstate[g];
                    float hn = (1.0f - z) * nn + z * hp;
                    hstate[g]     = hn;                        // pre-relu recurrent state
                    hseq[s][t][g] = hn > 0.0f ? hn : 0.0f;     // relu'd inter-layer activation
                }
                __syncthreads();
            }
        }
    }

    // epilogue: wave kq handles seq kq. slow_feat -> eps -> A_s, g_s
    {
        const int s = kq;
        float sf = sob[g];
        #pragma unroll 8
        for (int k = 0; k < GH; ++k) sf += hseq[s][31][k] * soW[k * GH + g];
        sfb[s][g] = sf;
        __syncthreads();
        float ep = s2sb[g];
        #pragma unroll 8
        for (int k = 0; k < GH; ++k) ep += sfb[s][k] * s2sW[k * GH + g];
        int q = seqs[s];
        if (g < HF) Abuf[q * HF + g] = sigmf(ep);
        else        Gbuf[q * HF + (g - HF)] = ep;
    }
}

// One thread per fast frame n (ns==nf so A/g row index == n). Runs the 32-step
// diagonal SSM in registers and overlap-adds via fp32 atomics (2-way contention max).
__global__ __launch_bounds__(256) void fast_ssm_kernel(
    const float* __restrict__ x,
    const float* __restrict__ Abuf, const float* __restrict__ Gbuf,
    const float* __restrict__ finW, const float* __restrict__ finb,
    const float* __restrict__ foutW, const float* __restrict__ foutb,
    float* __restrict__ out,
    int T, int nf, int NF)
{
    int n = blockIdx.x * blockDim.x + threadIdx.x;
    if (n >= NF) return;
    int b = n / nf, fi = n - b * nf;
    float Ar[HF], Gf[HF], Gb[HF], Fo[HF], h[HF];
    #pragma unroll
    for (int c = 0; c < HF; ++c) {
        float gv = Gbuf[n * HF + c];
        Ar[c] = Abuf[n * HF + c];
        Gf[c] = finW[c] * gv;     // fold g into the rank-1 input map
        Gb[c] = finb[c] * gv;     // bias applied BEFORE g-scale, per reference
        Fo[c] = foutW[c];
        h[c]  = 0.0f;
    }
    float fb = foutb[0];
    const float* xp = x + (size_t)b * T + fi * DS;
    float*       op = out + (size_t)b * T + fi * DS;
    for (int t = 0; t < LS; ++t) {
        float xv = xp[t];
        float sh = fb;
        #pragma unroll
        for (int c = 0; c < HF; ++c) {
            h[c] = Ar[c] * h[c] + (xv * Gf[c] + Gb[c]);
            sh  += h[c] * Fo[c];
        }
        atomicAdd(&op[t], sh);
    }
}

extern "C" void kernel_launch(void* const* d_in, const int* in_sizes, int n_in,
                              void* d_out, int out_size, void* d_ws, size_t ws_size,
                              hipStream_t stream)
{
    (void)n_in; (void)ws_size;
    const float* x     = (const float*)d_in[0];
    const float* siW   = (const float*)d_in[1];
    const float* sib   = (const float*)d_in[2];
    const float* Wih   = (const float*)d_in[3];
    const float* Whh   = (const float*)d_in[4];
    const float* bih   = (const float*)d_in[5];
    const float* bhh   = (const float*)d_in[6];
    const float* soW   = (const float*)d_in[7];
    const float* sob   = (const float*)d_in[8];
    const float* s2sW  = (const float*)d_in[9];
    const float* s2sb  = (const float*)d_in[10];
    const float* finW  = (const float*)d_in[11];
    const float* finb  = (const float*)d_in[12];
    const float* foutW = (const float*)d_in[13];
    const float* foutb = (const float*)d_in[14];

    int T  = in_sizes[0] / 2;          // B = 2
    int ns = (T - LS) / DS + 1;        // 3999
    int BS = 2 * ns;                   // 7998
    int nf = ns;                       // L_F==L_S, D_F==D_S -> identical framing
    int NF = 2 * nf;

    float* Abuf = (float*)d_ws;                 // (BS, 32)
    float* Gbuf = Abuf + (size_t)BS * HF;       // (BS, 32)   -> 2 MB total ws use

    hipMemsetAsync(d_out, 0, (size_t)out_size * sizeof(float), stream);

    slow_gru_kernel<<<dim3((BS + 3) / 4), dim3(256), 0, stream>>>(
        x, siW, sib, Wih, Whh, bih, bhh, soW, sob, s2sW, s2sb,
        Abuf, Gbuf, T, ns, BS);

    fast_ssm_kernel<<<dim3((NF + 255) / 256), dim3(256), 0, stream>>>(
        x, Abuf, Gbuf, finW, finb, foutW, foutb, (float*)d_out, T, nf, NF);
}

// Round 3
// 503.698 us; speedup vs baseline: 2.2296x; 2.2296x over previous
//
#include <hip/hip_runtime.h>

#define GH 64
#define LS 32
#define HF 32
#define DS 16

typedef short bf16x8 __attribute__((ext_vector_type(8)));
typedef float f32x4 __attribute__((ext_vector_type(4)));

#define MFMA16(a, b, c) __builtin_amdgcn_mfma_f32_16x16x32_bf16(a, b, c, 0, 0, 0)

__device__ __forceinline__ unsigned int f2bf(float f) {
    unsigned int u = __float_as_uint(f);
    return (u + 0x7FFFu + ((u >> 16) & 1u)) >> 16;   // RNE
}
__device__ __forceinline__ unsigned int relu2(unsigned int w) {
    // zero both bf16 halves whose sign bit is set (leaves -0.0: harmless in MFMA)
    unsigned int s = w & 0x80008000u;
    return w & ~(s - (s >> 15));
}
__device__ __forceinline__ float sigm(float x) {
    return __fdividef(1.0f, 1.0f + __expf(-x));
}
__device__ __forceinline__ float tanh_(float x) {
    return 1.0f - __fdividef(2.0f, __expf(2.0f * x) + 1.0f);
}

// A-fragment (16x16x32): lane holds A[m=lane&15][k=quad*8+j]. hseq layout:
// [t][seq(16)][ch(64)] bf16, 16B blocks XOR-swizzled by (seq&7) -> conflict-free
// b128 reads and ~2-way (free) b16 writes.
__device__ __forceinline__ bf16x8 ld_afrag(const unsigned short* hs, int t, int m,
                                           int quad, int half, bool relu) {
    int b   = half * 4 + quad;
    int idx = (((t << 4) + m) << 6) + ((b ^ (m & 7)) << 3);
    uint4 d = *reinterpret_cast<const uint4*>(hs + idx);
    if (relu) { d.x = relu2(d.x); d.y = relu2(d.y); d.z = relu2(d.z); d.w = relu2(d.w); }
    union { uint4 u; bf16x8 v; } cv; cv.u = d;
    return cv.v;
}

// B-fragment: lane holds B[k=quad*8+j][n=lane&15]; fp32 weights -> bf16 RNE.
__device__ __forceinline__ bf16x8 ld_bfrag(const float* __restrict__ W, int ldw,
                                           int col, int k0) {
    bf16x8 f;
    #pragma unroll
    for (int j = 0; j < 8; ++j)
        f[j] = (short)f2bf(W[(k0 + j) * ldw + col]);
    return f;
}

// One wave (64 threads) per block; block owns 16 sequences through all 4 GRU
// layers + the slow_out/s2s epilogue. hseq stores PRE-relu h (in-place across
// layers); consumers apply relu on load. Recurrent hc A-frags are re-reads of
// hseq[t-1] (no transpose buffer). Weight B-frags resident in VGPRs per layer.
__global__ __launch_bounds__(64, 1) void slow_gru_mfma(
    const float* __restrict__ x,
    const float* __restrict__ siW,  const float* __restrict__ sib,
    const float* __restrict__ Wih,  const float* __restrict__ Whh,
    const float* __restrict__ bih,  const float* __restrict__ bhh,
    const float* __restrict__ soW,  const float* __restrict__ sob,
    const float* __restrict__ s2sW, const float* __restrict__ s2sb,
    float* __restrict__ Abuf, float* __restrict__ Gbuf,
    int T, int ns, int BS)
{
    __shared__ __align__(16) unsigned short hseq[32 * 16 * 64];   // 64 KB exactly

    const int lane = threadIdx.x;
    const int c    = lane & 15;     // MFMA column (n) / A-row (m) index
    const int quad = lane >> 4;
    const int seqbase = blockIdx.x * 16;

    // ---- layer-0 pre-activations: hseq[t][s][ch] = x*siW + sib (pre-relu) ----
    for (int p = lane; p < 512; p += 64) {           // p = t*16 + seq
        int t = p >> 4, seq = p & 15;
        int q = seqbase + seq; if (q > BS - 1) q = BS - 1;
        int b  = (q >= ns) ? 1 : 0;
        int si = q - b * ns;
        float xv = x[b * T + si * DS + t];
        int base = (((t << 4) + seq) << 6);
        int sw   = seq & 7;
        #pragma unroll
        for (int dp = 0; dp < 32; ++dp) {
            int ch = dp << 1;
            float v0 = fmaf(xv, siW[ch],     sib[ch]);
            float v1 = fmaf(xv, siW[ch + 1], sib[ch + 1]);
            unsigned int w = f2bf(v0) | (f2bf(v1) << 16);
            int idx = base + ((((ch >> 3) ^ sw)) << 3) + (ch & 7);   // even -> dword
            *reinterpret_cast<unsigned int*>(&hseq[idx]) = w;
        }
    }
    __syncthreads();

    float hprev[4][4];   // hc in C-layout: [n-tile][reg] = hc[quad*4+i][jt*16+c]

    for (int l = 0; l < 4; ++l) {
        const float* Wi = Wih + (size_t)l * GH * 192;
        const float* Wh = Whh + (size_t)l * GH * 192;

        // resident B-fragments: 6 gates-matrices x 4 n-tiles x 2 k-chunks
        bf16x8 BiR[4][2], BiZ[4][2], BiN[4][2], BhR[4][2], BhZ[4][2], BhN[4][2];
        #pragma unroll
        for (int jt = 0; jt < 4; ++jt)
            #pragma unroll
            for (int kc = 0; kc < 2; ++kc) {
                int k0 = kc * 32 + quad * 8;
                BiR[jt][kc] = ld_bfrag(Wi, 192,       jt * 16 + c, k0);
                BiZ[jt][kc] = ld_bfrag(Wi, 192,  64 + jt * 16 + c, k0);
                BiN[jt][kc] = ld_bfrag(Wi, 192, 128 + jt * 16 + c, k0);
                BhR[jt][kc] = ld_bfrag(Wh, 192,       jt * 16 + c, k0);
                BhZ[jt][kc] = ld_bfrag(Wh, 192,  64 + jt * 16 + c, k0);
                BhN[jt][kc] = ld_bfrag(Wh, 192, 128 + jt * 16 + c, k0);
            }
        float bR[4], bZ[4], bNI[4], bNH[4];
        #pragma unroll
        for (int jt = 0; jt < 4; ++jt) {
            int col = jt * 16 + c;
            bR[jt]  = bih[l * 192 + col]      + bhh[l * 192 + col];       // merge ok
            bZ[jt]  = bih[l * 192 + 64 + col] + bhh[l * 192 + 64 + col];  // merge ok
            bNI[jt] = bih[l * 192 + 128 + col];   // n-gate: keep ih / hh separate
            bNH[jt] = bhh[l * 192 + 128 + col];   // (reference: tanh(xg_n + r*hg_n))
        }
        #pragma unroll
        for (int jt = 0; jt < 4; ++jt)
            #pragma unroll
            for (int i = 0; i < 4; ++i) hprev[jt][i] = 0.0f;

        for (int t = 0; t < LS; ++t) {
            // input A-frags: previous layer's hseq[t], relu applied on load
            bf16x8 a0 = ld_afrag(hseq, t, c, quad, 0, true);
            bf16x8 a1 = ld_afrag(hseq, t, c, quad, 1, true);

            f32x4 aR[4], aZ[4], aNI[4], aNH[4];
            #pragma unroll
            for (int jt = 0; jt < 4; ++jt) {
                aR[jt]  = (f32x4){bR[jt],  bR[jt],  bR[jt],  bR[jt]};
                aZ[jt]  = (f32x4){bZ[jt],  bZ[jt],  bZ[jt],  bZ[jt]};
                aNI[jt] = (f32x4){bNI[jt], bNI[jt], bNI[jt], bNI[jt]};
                aNH[jt] = (f32x4){bNH[jt], bNH[jt], bNH[jt], bNH[jt]};
            }
            #pragma unroll
            for (int jt = 0; jt < 4; ++jt) {
                aR[jt]  = MFMA16(a0, BiR[jt][0], aR[jt]);
                aR[jt]  = MFMA16(a1, BiR[jt][1], aR[jt]);
                aZ[jt]  = MFMA16(a0, BiZ[jt][0], aZ[jt]);
                aZ[jt]  = MFMA16(a1, BiZ[jt][1], aZ[jt]);
                aNI[jt] = MFMA16(a0, BiN[jt][0], aNI[jt]);
                aNI[jt] = MFMA16(a1, BiN[jt][1], aNI[jt]);
            }
            if (t > 0) {
                // recurrent A-frags: pre-relu hn written at step t-1 (no relu)
                bf16x8 h0 = ld_afrag(hseq, t - 1, c, quad, 0, false);
                bf16x8 h1 = ld_afrag(hseq, t - 1, c, quad, 1, false);
                #pragma unroll
                for (int jt = 0; jt < 4; ++jt) {
                    aR[jt]  = MFMA16(h0, BhR[jt][0], aR[jt]);
                    aR[jt]  = MFMA16(h1, BhR[jt][1], aR[jt]);
                    aZ[jt]  = MFMA16(h0, BhZ[jt][0], aZ[jt]);
                    aZ[jt]  = MFMA16(h1, BhZ[jt][1], aZ[jt]);
                    aNH[jt] = MFMA16(h0, BhN[jt][0], aNH[jt]);
                    aNH[jt] = MFMA16(h1, BhN[jt][1], aNH[jt]);
                }
            }
            // gates in C-layout (col=lane&15, row=quad*4+i), hc stays in regs
            #pragma unroll
            for (int jt = 0; jt < 4; ++jt)
                #pragma unroll
                for (int i = 0; i < 4; ++i) {
                    float r  = sigm(aR[jt][i]);
                    float z  = sigm(aZ[jt][i]);
                    float n  = tanh_(fmaf(r, aNH[jt][i], aNI[jt][i]));
                    float hn = fmaf(z, hprev[jt][i] - n, n);
                    hprev[jt][i] = hn;
                    int row = quad * 4 + i;
                    int ch  = jt * 16 + c;
                    int idx = (((t << 4) + row) << 6)
                            + ((((ch >> 3) ^ (row & 7))) << 3) + (ch & 7);
                    hseq[idx] = (unsigned short)f2bf(hn);   // store PRE-relu
                }
            __syncthreads();   // order scattered b16 writes vs next step's b128 reads
        }
    }

    // ---- epilogue: slow_feat = relu(h3[31]) @ soW + sob; eps = sf @ s2sW + s2sb ----
    {
        bf16x8 a0 = ld_afrag(hseq, 31, c, quad, 0, true);
        bf16x8 a1 = ld_afrag(hseq, 31, c, quad, 1, true);
        bf16x8 Bso[4][2], Bs2[4][2];
        #pragma unroll
        for (int jt = 0; jt < 4; ++jt)
            #pragma unroll
            for (int kc = 0; kc < 2; ++kc) {
                int k0 = kc * 32 + quad * 8;
                Bso[jt][kc] = ld_bfrag(soW,  GH, jt * 16 + c, k0);
                Bs2[jt][kc] = ld_bfrag(s2sW, 2 * HF, jt * 16 + c, k0);
            }
        f32x4 accS[4];
        #pragma unroll
        for (int jt = 0; jt < 4; ++jt) {
            float bv = sob[jt * 16 + c];
            accS[jt] = (f32x4){bv, bv, bv, bv};
            accS[jt] = MFMA16(a0, Bso[jt][0], accS[jt]);
            accS[jt] = MFMA16(a1, Bso[jt][1], accS[jt]);
        }
        __syncthreads();
        // stage slow_feat (bf16) into hseq rows 0..15 (layers done; safe to reuse)
        #pragma unroll
        for (int jt = 0; jt < 4; ++jt)
            #pragma unroll
            for (int i = 0; i < 4; ++i) {
                int row = quad * 4 + i;
                int ch  = jt * 16 + c;
                int idx = (row << 6) + ((((ch >> 3) ^ (row & 7))) << 3) + (ch & 7);
                hseq[idx] = (unsigned short)f2bf(accS[jt][i]);
            }
        __syncthreads();
        bf16x8 s0 = ld_afrag(hseq, 0, c, quad, 0, false);
        bf16x8 s1 = ld_afrag(hseq, 0, c, quad, 1, false);
        f32x4 accE[4];
        #pragma unroll
        for (int jt = 0; jt < 4; ++jt) {
            float bv = s2sb[jt * 16 + c];
            accE[jt] = (f32x4){bv, bv, bv, bv};
            accE[jt] = MFMA16(s0, Bs2[jt][0], accE[jt]);
            accE[jt] = MFMA16(s1, Bs2[jt][1], accE[jt]);
        }
        #pragma unroll
        for (int jt = 0; jt < 4; ++jt)
            #pragma unroll
            for (int i = 0; i < 4; ++i) {
                int row = quad * 4 + i;
                int q = seqbase + row; if (q > BS - 1) q = BS - 1;  // dup rows: same data
                float v = accE[jt][i];
                if (jt < 2) Abuf[q * HF + jt * 16 + c] = sigm(v);
                else        Gbuf[q * HF + (jt - 2) * 16 + c] = v;
            }
    }
}

// One thread per fast frame n (ns==nf). 32-step diagonal SSM in registers,
// overlap-add via fp32 atomics (max 2-way contention).
__global__ __launch_bounds__(256) void fast_ssm_kernel(
    const float* __restrict__ x,
    const float* __restrict__ Abuf, const float* __restrict__ Gbuf,
    const float* __restrict__ finW, const float* __restrict__ finb,
    const float* __restrict__ foutW, const float* __restrict__ foutb,
    float* __restrict__ out,
    int T, int nf, int NF)
{
    int n = blockIdx.x * blockDim.x + threadIdx.x;
    if (n >= NF) return;
    int b = n / nf, fi = n - b * nf;
    float Ar[HF], Gf[HF], Gb[HF], Fo[HF], h[HF];
    #pragma unroll
    for (int cc = 0; cc < HF; ++cc) {
        float gv = Gbuf[n * HF + cc];
        Ar[cc] = Abuf[n * HF + cc];
        Gf[cc] = finW[cc] * gv;
        Gb[cc] = finb[cc] * gv;
        Fo[cc] = foutW[cc];
        h[cc]  = 0.0f;
    }
    float fb = foutb[0];
    const float* xp = x + (size_t)b * T + fi * DS;
    float*       op = out + (size_t)b * T + fi * DS;
    for (int t = 0; t < LS; ++t) {
        float xv = xp[t];
        float sh = fb;
        #pragma unroll
        for (int cc = 0; cc < HF; ++cc) {
            h[cc] = Ar[cc] * h[cc] + (xv * Gf[cc] + Gb[cc]);
            sh   += h[cc] * Fo[cc];
        }
        atomicAdd(&op[t], sh);
    }
}

extern "C" void kernel_launch(void* const* d_in, const int* in_sizes, int n_in,
                              void* d_out, int out_size, void* d_ws, size_t ws_size,
                              hipStream_t stream)
{
    (void)n_in; (void)ws_size;
    const float* x     = (const float*)d_in[0];
    const float* siW   = (const float*)d_in[1];
    const float* sib   = (const float*)d_in[2];
    const float* Wih   = (const float*)d_in[3];
    const float* Whh   = (const float*)d_in[4];
    const float* bih   = (const float*)d_in[5];
    const float* bhh   = (const float*)d_in[6];
    const float* soW   = (const float*)d_in[7];
    const float* sob   = (const float*)d_in[8];
    const float* s2sW  = (const float*)d_in[9];
    const float* s2sb  = (const float*)d_in[10];
    const float* finW  = (const float*)d_in[11];
    const float* finb  = (const float*)d_in[12];
    const float* foutW = (const float*)d_in[13];
    const float* foutb = (const float*)d_in[14];

    int T  = in_sizes[0] / 2;          // B = 2
    int ns = (T - LS) / DS + 1;        // 3999
    int BS = 2 * ns;                   // 7998
    int nf = ns;
    int NF = 2 * nf;

    float* Abuf = (float*)d_ws;                 // (BS, 32)
    float* Gbuf = Abuf + (size_t)BS * HF;       // (BS, 32)

    (void)hipMemsetAsync(d_out, 0, (size_t)out_size * sizeof(float), stream);

    slow_gru_mfma<<<dim3((BS + 15) / 16), dim3(64), 0, stream>>>(
        x, siW, sib, Wih, Whh, bih, bhh, soW, sob, s2sW, s2sb,
        Abuf, Gbuf, T, ns, BS);

    fast_ssm_kernel<<<dim3((NF + 255) / 256), dim3(256), 0, stream>>>(
        x, Abuf, Gbuf, finW, finb, foutW, foutb, (float*)d_out, T, nf, NF);
}

// Round 4
// 258.786 us; speedup vs baseline: 4.3396x; 1.9464x over previous
//
#include <hip/hip_runtime.h>

#define GH 64
#define LS 32
#define HF 32
#define DS 16

typedef short bf16x8 __attribute__((ext_vector_type(8)));
typedef float f32x4 __attribute__((ext_vector_type(4)));

#define MFMA16(a, b, c) __builtin_amdgcn_mfma_f32_16x16x32_bf16(a, b, c, 0, 0, 0)

__device__ __forceinline__ unsigned int f2bf(float f) {
    unsigned int u = __float_as_uint(f);
    return (u + 0x7FFFu + ((u >> 16) & 1u)) >> 16;   // RNE
}
__device__ __forceinline__ unsigned int relu2(unsigned int w) {
    unsigned int s = w & 0x80008000u;
    return w & ~(s - (s >> 15));     // negatives -> -0.0 (harmless in MFMA)
}
__device__ __forceinline__ float sigm(float x) {
    return __fdividef(1.0f, 1.0f + __expf(-x));
}
__device__ __forceinline__ float tanh_(float x) {
    return 1.0f - __fdividef(2.0f, __expf(2.0f * x) + 1.0f);
}

// A-fragment (16x16x32): lane holds A[m=lane&15][k=quad*8+j]. hseq layout:
// [t][seq(16)][ch(64)] bf16, 16B blocks XOR-swizzled by (seq&7) -> conflict-free
// b128 reads, 2-way (free) b16 writes.
__device__ __forceinline__ bf16x8 ld_afrag(const unsigned short* hs, int t, int m,
                                           int quad, int half, bool relu) {
    int b   = half * 4 + quad;
    int idx = (((t << 4) + m) << 6) + ((b ^ (m & 7)) << 3);
    uint4 d = *reinterpret_cast<const uint4*>(hs + idx);
    if (relu) { d.x = relu2(d.x); d.y = relu2(d.y); d.z = relu2(d.z); d.w = relu2(d.w); }
    union { uint4 u; bf16x8 v; } cv; cv.u = d;
    return cv.v;
}

// B-fragment: lane holds B[k=quad*8+j][n]; fp32 weights -> bf16 RNE.
__device__ __forceinline__ bf16x8 ld_bfrag(const float* __restrict__ W, int ldw,
                                           int col, int k0) {
    bf16x8 f;
    #pragma unroll
    for (int j = 0; j < 8; ++j)
        f[j] = (short)f2bf(W[(k0 + j) * ldw + col]);
    return f;
}

// Block = 4 waves x 64; block owns 16 sequences. Wave jt owns gate-column tile
// [jt*16, jt*16+16): its B-frags (48 VGPRs), its C-layout accs, its hprev.
// GRU gate math is elementwise in (seq, channel) -> no cross-wave data except
// hseq (all channels) via LDS. Two barriers/step: read-fence then write-fence.
// hseq stores PRE-relu h in-place across layers; relu applied on A-frag load.
__global__ __launch_bounds__(256, 2) void slow_gru_mfma(
    const float* __restrict__ x,
    const float* __restrict__ siW,  const float* __restrict__ sib,
    const float* __restrict__ Wih,  const float* __restrict__ Whh,
    const float* __restrict__ bih,  const float* __restrict__ bhh,
    const float* __restrict__ soW,  const float* __restrict__ sob,
    const float* __restrict__ s2sW, const float* __restrict__ s2sb,
    float* __restrict__ Abuf, float* __restrict__ Gbuf,
    int T, int ns, int BS)
{
    __shared__ __align__(16) unsigned short hseq[32 * 16 * 64];   // 64 KB exactly

    const int tid  = threadIdx.x;
    const int lane = tid & 63;
    const int jt   = tid >> 6;          // wave id == n-tile
    const int c    = lane & 15;
    const int quad = lane >> 4;
    const int col  = jt * 16 + c;       // this lane's gate/h column
    const int seqbase = blockIdx.x * 16;

    // ---- layer-0 pre-activations: hseq[t][s][ch] = x*siW + sib (pre-relu) ----
    for (int p = tid; p < 512; p += 256) {           // p = t*16 + seq
        int t = p >> 4, seq = p & 15;
        int q = seqbase + seq; if (q > BS - 1) q = BS - 1;
        int b  = (q >= ns) ? 1 : 0;
        int si = q - b * ns;
        float xv = x[b * T + si * DS + t];
        int base = (((t << 4) + seq) << 6);
        int sw   = seq & 7;
        #pragma unroll
        for (int dp = 0; dp < 32; ++dp) {
            int ch = dp << 1;
            float v0 = fmaf(xv, siW[ch],     sib[ch]);
            float v1 = fmaf(xv, siW[ch + 1], sib[ch + 1]);
            unsigned int w = f2bf(v0) | (f2bf(v1) << 16);
            int idx = base + ((((ch >> 3) ^ sw)) << 3) + (ch & 7);
            *reinterpret_cast<unsigned int*>(&hseq[idx]) = w;
        }
    }
    __syncthreads();

    float hprev[4];   // hc in C-layout: hprev[i] = hc[quad*4+i][col]

    for (int l = 0; l < 4; ++l) {
        const float* Wi = Wih + (size_t)l * GH * 192;
        const float* Wh = Whh + (size_t)l * GH * 192;

        // resident B-fragments for this wave's 16 columns: 6 matrices x 2 k-chunks
        bf16x8 BiR[2], BiZ[2], BiN[2], BhR[2], BhZ[2], BhN[2];
        #pragma unroll
        for (int kc = 0; kc < 2; ++kc) {
            int k0 = kc * 32 + quad * 8;
            BiR[kc] = ld_bfrag(Wi, 192,       col, k0);
            BiZ[kc] = ld_bfrag(Wi, 192,  64 + col, k0);
            BiN[kc] = ld_bfrag(Wi, 192, 128 + col, k0);
            BhR[kc] = ld_bfrag(Wh, 192,       col, k0);
            BhZ[kc] = ld_bfrag(Wh, 192,  64 + col, k0);
            BhN[kc] = ld_bfrag(Wh, 192, 128 + col, k0);
        }
        float bR  = bih[l * 192 + col]      + bhh[l * 192 + col];
        float bZ  = bih[l * 192 + 64 + col] + bhh[l * 192 + 64 + col];
        float bNI = bih[l * 192 + 128 + col];   // n-gate ih/hh kept separate:
        float bNH = bhh[l * 192 + 128 + col];   // tanh(xg_n + r*hg_n)

        #pragma unroll
        for (int i = 0; i < 4; ++i) hprev[i] = 0.0f;

        #pragma unroll 1
        for (int t = 0; t < LS; ++t) {
            bf16x8 a0 = ld_afrag(hseq, t, c, quad, 0, true);    // prev-layer input
            bf16x8 a1 = ld_afrag(hseq, t, c, quad, 1, true);
            bf16x8 h0, h1;
            if (t > 0) {                                        // recurrent (pre-relu)
                h0 = ld_afrag(hseq, t - 1, c, quad, 0, false);
                h1 = ld_afrag(hseq, t - 1, c, quad, 1, false);
            }
            __syncthreads();   // read-fence: all waves done reading hseq[t]

            f32x4 aR  = (f32x4){bR,  bR,  bR,  bR};
            f32x4 aZ  = (f32x4){bZ,  bZ,  bZ,  bZ};
            f32x4 aNI = (f32x4){bNI, bNI, bNI, bNI};
            f32x4 aNH = (f32x4){bNH, bNH, bNH, bNH};
            aR  = MFMA16(a0, BiR[0], aR);
            aR  = MFMA16(a1, BiR[1], aR);
            aZ  = MFMA16(a0, BiZ[0], aZ);
            aZ  = MFMA16(a1, BiZ[1], aZ);
            aNI = MFMA16(a0, BiN[0], aNI);
            aNI = MFMA16(a1, BiN[1], aNI);
            if (t > 0) {
                aR  = MFMA16(h0, BhR[0], aR);
                aR  = MFMA16(h1, BhR[1], aR);
                aZ  = MFMA16(h0, BhZ[0], aZ);
                aZ  = MFMA16(h1, BhZ[1], aZ);
                aNH = MFMA16(h0, BhN[0], aNH);
                aNH = MFMA16(h1, BhN[1], aNH);
            }
            #pragma unroll
            for (int i = 0; i < 4; ++i) {
                float r  = sigm(aR[i]);
                float z  = sigm(aZ[i]);
                float n  = tanh_(fmaf(r, aNH[i], aNI[i]));
                float hn = fmaf(z, hprev[i] - n, n);
                hprev[i] = hn;
                int row = quad * 4 + i;
                int idx = (((t << 4) + row) << 6)
                        + ((((col >> 3) ^ (row & 7))) << 3) + (col & 7);
                hseq[idx] = (unsigned short)f2bf(hn);   // store PRE-relu
            }
            __syncthreads();   // write-fence before next step's reads
        }
    }

    // ---- epilogue: slow_feat = relu(h3[31]) @ soW + sob; eps = sf @ s2sW + s2sb ----
    {
        bf16x8 a0 = ld_afrag(hseq, 31, c, quad, 0, true);
        bf16x8 a1 = ld_afrag(hseq, 31, c, quad, 1, true);
        bf16x8 Bso[2], Bs2[2];
        #pragma unroll
        for (int kc = 0; kc < 2; ++kc) {
            int k0 = kc * 32 + quad * 8;
            Bso[kc] = ld_bfrag(soW,  GH,     col, k0);
            Bs2[kc] = ld_bfrag(s2sW, 2 * HF, col, k0);
        }
        float bv = sob[col];
        f32x4 accS = (f32x4){bv, bv, bv, bv};
        accS = MFMA16(a0, Bso[0], accS);
        accS = MFMA16(a1, Bso[1], accS);
        // stage slow_feat (bf16) into hseq t=0 rows (no live data there anymore)
        #pragma unroll
        for (int i = 0; i < 4; ++i) {
            int row = quad * 4 + i;
            int idx = (row << 6) + ((((col >> 3) ^ (row & 7))) << 3) + (col & 7);
            hseq[idx] = (unsigned short)f2bf(accS[i]);
        }
        __syncthreads();
        bf16x8 s0 = ld_afrag(hseq, 0, c, quad, 0, false);
        bf16x8 s1 = ld_afrag(hseq, 0, c, quad, 1, false);
        float ev = s2sb[col];
        f32x4 accE = (f32x4){ev, ev, ev, ev};
        accE = MFMA16(s0, Bs2[0], accE);
        accE = MFMA16(s1, Bs2[1], accE);
        #pragma unroll
        for (int i = 0; i < 4; ++i) {
            int row = quad * 4 + i;
            int q = seqbase + row; if (q > BS - 1) q = BS - 1;  // dup rows: same data
            float v = accE[i];
            if (jt < 2) Abuf[q * HF + col] = sigm(v);
            else        Gbuf[q * HF + (col - HF)] = v;
        }
    }
}

// One thread per fast frame n (ns==nf). 32-step diagonal SSM in registers,
// overlap-add via fp32 atomics (max 2-way contention).
__global__ __launch_bounds__(256) void fast_ssm_kernel(
    const float* __restrict__ x,
    const float* __restrict__ Abuf, const float* __restrict__ Gbuf,
    const float* __restrict__ finW, const float* __restrict__ finb,
    const float* __restrict__ foutW, const float* __restrict__ foutb,
    float* __restrict__ out,
    int T, int nf, int NF)
{
    int n = blockIdx.x * blockDim.x + threadIdx.x;
    if (n >= NF) return;
    int b = n / nf, fi = n - b * nf;
    float Ar[HF], Gf[HF], Gb[HF], Fo[HF], h[HF];
    #pragma unroll
    for (int cc = 0; cc < HF; ++cc) {
        float gv = Gbuf[n * HF + cc];
        Ar[cc] = Abuf[n * HF + cc];
        Gf[cc] = finW[cc] * gv;
        Gb[cc] = finb[cc] * gv;
        Fo[cc] = foutW[cc];
        h[cc]  = 0.0f;
    }
    float fb = foutb[0];
    const float* xp = x + (size_t)b * T + fi * DS;
    float*       op = out + (size_t)b * T + fi * DS;
    for (int t = 0; t < LS; ++t) {
        float xv = xp[t];
        float sh = fb;
        #pragma unroll
        for (int cc = 0; cc < HF; ++cc) {
            h[cc] = Ar[cc] * h[cc] + (xv * Gf[cc] + Gb[cc]);
            sh   += h[cc] * Fo[cc];
        }
        atomicAdd(&op[t], sh);
    }
}

extern "C" void kernel_launch(void* const* d_in, const int* in_sizes, int n_in,
                              void* d_out, int out_size, void* d_ws, size_t ws_size,
                              hipStream_t stream)
{
    (void)n_in; (void)ws_size;
    const float* x     = (const float*)d_in[0];
    const float* siW   = (const float*)d_in[1];
    const float* sib   = (const float*)d_in[2];
    const float* Wih   = (const float*)d_in[3];
    const float* Whh   = (const float*)d_in[4];
    const float* bih   = (const float*)d_in[5];
    const float* bhh   = (const float*)d_in[6];
    const float* soW   = (const float*)d_in[7];
    const float* sob   = (const float*)d_in[8];
    const float* s2sW  = (const float*)d_in[9];
    const float* s2sb  = (const float*)d_in[10];
    const float* finW  = (const float*)d_in[11];
    const float* finb  = (const float*)d_in[12];
    const float* foutW = (const float*)d_in[13];
    const float* foutb = (const float*)d_in[14];

    int T  = in_sizes[0] / 2;          // B = 2
    int ns = (T - LS) / DS + 1;        // 3999
    int BS = 2 * ns;                   // 7998
    int nf = ns;
    int NF = 2 * nf;

    float* Abuf = (float*)d_ws;                 // (BS, 32)
    float* Gbuf = Abuf + (size_t)BS * HF;       // (BS, 32)

    (void)hipMemsetAsync(d_out, 0, (size_t)out_size * sizeof(float), stream);

    slow_gru_mfma<<<dim3((BS + 15) / 16), dim3(256), 0, stream>>>(
        x, siW, sib, Wih, Whh, bih, bhh, soW, sob, s2sW, s2sb,
        Abuf, Gbuf, T, ns, BS);

    fast_ssm_kernel<<<dim3((NF + 255) / 256), dim3(256), 0, stream>>>(
        x, Abuf, Gbuf, finW, finb, foutW, foutb, (float*)d_out, T, nf, NF);
}

// Round 5
// 238.868 us; speedup vs baseline: 4.7015x; 1.0834x over previous
//
#include <hip/hip_runtime.h>

#define GH 64
#define LS 32
#define HF 32
#define DS 16

typedef short bf16x8 __attribute__((ext_vector_type(8)));
typedef float f32x4 __attribute__((ext_vector_type(4)));

#define MFMA16(a, b, c) __builtin_amdgcn_mfma_f32_16x16x32_bf16(a, b, c, 0, 0, 0)

__device__ __forceinline__ unsigned int f2bf(float f) {
    unsigned int u = __float_as_uint(f);
    return (u + 0x7FFFu + ((u >> 16) & 1u)) >> 16;   // RNE
}
__device__ __forceinline__ unsigned int relu2(unsigned int w) {
    unsigned int s = w & 0x80008000u;
    return w & ~(s - (s >> 15));     // negatives -> -0.0 (harmless in MFMA)
}
__device__ __forceinline__ float sigm(float x) {
    return __fdividef(1.0f, 1.0f + __expf(-x));
}
__device__ __forceinline__ float tanh_(float x) {
    return 1.0f - __fdividef(2.0f, __expf(2.0f * x) + 1.0f);
}

// A-fragment (16x16x32) from a 16x64 bf16 tile, XOR-swizzled 16B blocks:
// element (seq,ch) at seq*64 + (((ch>>3)^(seq&7))<<3) + (ch&7). Conflict-free
// b128 reads (R4: SQ_LDS_BANK_CONFLICT == 0), 2-way-free b16 writes.
__device__ __forceinline__ bf16x8 ld_afrag(const unsigned short* base, int m,
                                           int quad, int half, bool relu) {
    int b   = half * 4 + quad;
    int idx = (m << 6) + ((b ^ (m & 7)) << 3);
    uint4 d = *reinterpret_cast<const uint4*>(base + idx);
    if (relu) { d.x = relu2(d.x); d.y = relu2(d.y); d.z = relu2(d.z); d.w = relu2(d.w); }
    union { uint4 u; bf16x8 v; } cv; cv.u = d;
    return cv.v;
}

// B-fragment: lane holds B[k=quad*8+j][n]; fp32 weights -> bf16 RNE.
__device__ __forceinline__ bf16x8 ld_bfrag(const float* __restrict__ W, int ldw,
                                           int col, int k0) {
    bf16x8 f;
    #pragma unroll
    for (int j = 0; j < 8; ++j)
        f[j] = (short)f2bf(W[(k0 + j) * ldw + col]);
    return f;
}

// pack two f32 -> (bf16(v1)<<16)|bf16(v0) by truncation: single v_perm_b32
__device__ __forceinline__ unsigned int pack_trunc(float v0, float v1) {
    return __builtin_amdgcn_perm(__float_as_uint(v1), __float_as_uint(v0),
                                 0x07060302u);
}

// Layer-0 input A-frag built on the fly: relu(xv*siW[ch]+sib[ch]) for 8 chans.
__device__ __forceinline__ bf16x8 build_l0(float xv, const float* w, const float* b) {
    float4 w0 = reinterpret_cast<const float4*>(w)[0];
    float4 w1 = reinterpret_cast<const float4*>(w)[1];
    float4 b0 = reinterpret_cast<const float4*>(b)[0];
    float4 b1 = reinterpret_cast<const float4*>(b)[1];
    float v0 = fmaxf(fmaf(xv, w0.x, b0.x), 0.0f);
    float v1 = fmaxf(fmaf(xv, w0.y, b0.y), 0.0f);
    float v2 = fmaxf(fmaf(xv, w0.z, b0.z), 0.0f);
    float v3 = fmaxf(fmaf(xv, w0.w, b0.w), 0.0f);
    float v4 = fmaxf(fmaf(xv, w1.x, b1.x), 0.0f);
    float v5 = fmaxf(fmaf(xv, w1.y, b1.y), 0.0f);
    float v6 = fmaxf(fmaf(xv, w1.z, b1.z), 0.0f);
    float v7 = fmaxf(fmaf(xv, w1.w, b1.w), 0.0f);
    union { uint4 u; bf16x8 v; } cv;
    cv.u.x = pack_trunc(v0, v1);
    cv.u.y = pack_trunc(v2, v3);
    cv.u.z = pack_trunc(v4, v5);
    cv.u.w = pack_trunc(v6, v7);
    return cv.v;
}

// 1024 threads = 16 waves = (layer l: 0..3) x (col-tile jt: 0..3). Block owns
// 16 sequences end-to-end: layer-pipelined GRU (step tau: layer l does
// t=tau-l; 2-slot activation ring => ONE barrier/step, 35 steps), then fused
// slow_out/s2s epilogue and the fast diagonal SSM with overlap-add atomics.
// SIMD balance: wave w -> SIMD w&3, so each SIMD hosts one wave per layer.
__global__ __launch_bounds__(1024, 4) void slowfast_fused(
    const float* __restrict__ x,
    const float* __restrict__ siW,  const float* __restrict__ sib,
    const float* __restrict__ Wih,  const float* __restrict__ Whh,
    const float* __restrict__ bih,  const float* __restrict__ bhh,
    const float* __restrict__ soW,  const float* __restrict__ sob,
    const float* __restrict__ s2sW, const float* __restrict__ s2sb,
    const float* __restrict__ finW, const float* __restrict__ finb,
    const float* __restrict__ foutW, const float* __restrict__ foutb,
    float* __restrict__ out,
    int T, int ns, int BS)
{
    __shared__ __align__(16) unsigned short buf[4][2][16 * 64];  // 16 KB ring
    __shared__ float xs[16 * 33];      // x windows, pad-33 (bank spread)
    __shared__ float swb[128];         // siW[64] | sib[64]
    __shared__ float AG[16 * 65];      // A_s | g_s staging (pad-65)

    const int tid  = threadIdx.x;
    const int lane = tid & 63;
    const int wid  = tid >> 6;
    const int l    = wid >> 2;          // layer
    const int jt   = wid & 3;           // col tile
    const int c    = lane & 15;
    const int quad = lane >> 4;
    const int col  = jt * 16 + c;
    const int seqbase = blockIdx.x * 16;

    // ---- stage x windows + slow_in weights ----
    if (tid < 512) {
        int seq = tid >> 5, t = tid & 31;
        int q = seqbase + seq; if (q > BS - 1) q = BS - 1;
        int b  = (q >= ns) ? 1 : 0;
        int si = q - b * ns;
        xs[seq * 33 + t] = x[b * T + si * DS + t];
    }
    if (tid < 64) { swb[tid] = siW[tid]; swb[64 + tid] = sib[tid]; }

    // ---- per-wave resident B-fragments (loaded once; 48 VGPRs) ----
    const float* Wi = Wih + (size_t)l * GH * 192;
    const float* Wh = Whh + (size_t)l * GH * 192;
    bf16x8 BiR[2], BiZ[2], BiN[2], BhR[2], BhZ[2], BhN[2];
    #pragma unroll
    for (int kc = 0; kc < 2; ++kc) {
        int k0 = kc * 32 + quad * 8;
        BiR[kc] = ld_bfrag(Wi, 192,       col, k0);
        BiZ[kc] = ld_bfrag(Wi, 192,  64 + col, k0);
        BiN[kc] = ld_bfrag(Wi, 192, 128 + col, k0);
        BhR[kc] = ld_bfrag(Wh, 192,       col, k0);
        BhZ[kc] = ld_bfrag(Wh, 192,  64 + col, k0);
        BhN[kc] = ld_bfrag(Wh, 192, 128 + col, k0);
    }
    float bR  = bih[l * 192 + col]      + bhh[l * 192 + col];
    float bZ  = bih[l * 192 + 64 + col] + bhh[l * 192 + 64 + col];
    float bNI = bih[l * 192 + 128 + col];   // n-gate ih/hh separate:
    float bNH = bhh[l * 192 + 128 + col];   // tanh(xg_n + r*hg_n)

    float hprev[4] = {0.0f, 0.0f, 0.0f, 0.0f};

    __syncthreads();

    // ---- pipelined main loop: one barrier per global step ----
    #pragma unroll 1
    for (int tau = 0; tau < LS + 3; ++tau) {
        int t = tau - l;
        if (t >= 0 && t < LS) {
            bf16x8 a0, a1, h0, h1;
            if (l == 0) {
                float xv = xs[c * 33 + t];
                a0 = build_l0(xv, &swb[quad * 8],      &swb[64 + quad * 8]);
                a1 = build_l0(xv, &swb[32 + quad * 8], &swb[96 + quad * 8]);
            } else {
                const unsigned short* ab = buf[l - 1][t & 1];
                a0 = ld_afrag(ab, c, quad, 0, true);    // relu(prev-layer h)
                a1 = ld_afrag(ab, c, quad, 1, true);
            }
            if (t > 0) {
                const unsigned short* hb = buf[l][(t - 1) & 1];
                h0 = ld_afrag(hb, c, quad, 0, false);   // pre-relu recurrent
                h1 = ld_afrag(hb, c, quad, 1, false);
            }
            f32x4 aR  = (f32x4){bR,  bR,  bR,  bR};
            f32x4 aZ  = (f32x4){bZ,  bZ,  bZ,  bZ};
            f32x4 aNI = (f32x4){bNI, bNI, bNI, bNI};
            f32x4 aNH = (f32x4){bNH, bNH, bNH, bNH};
            aR  = MFMA16(a0, BiR[0], aR);
            aR  = MFMA16(a1, BiR[1], aR);
            aZ  = MFMA16(a0, BiZ[0], aZ);
            aZ  = MFMA16(a1, BiZ[1], aZ);
            aNI = MFMA16(a0, BiN[0], aNI);
            aNI = MFMA16(a1, BiN[1], aNI);
            if (t > 0) {
                aR  = MFMA16(h0, BhR[0], aR);
                aR  = MFMA16(h1, BhR[1], aR);
                aZ  = MFMA16(h0, BhZ[0], aZ);
                aZ  = MFMA16(h1, BhZ[1], aZ);
                aNH = MFMA16(h0, BhN[0], aNH);
                aNH = MFMA16(h1, BhN[1], aNH);
            }
            unsigned short* wb = buf[l][t & 1];
            #pragma unroll
            for (int i = 0; i < 4; ++i) {
                float r  = sigm(aR[i]);
                float z  = sigm(aZ[i]);
                float n  = tanh_(fmaf(r, aNH[i], aNI[i]));
                float hn = fmaf(z, hprev[i] - n, n);
                hprev[i] = hn;
                int row = quad * 4 + i;
                int idx = (row << 6) + ((((col >> 3) ^ (row & 7))) << 3) + (col & 7);
                wb[idx] = (unsigned short)f2bf(hn);     // PRE-relu
            }
        }
        __syncthreads();   // slot written at tau is read at tau+1
    }

    // ---- fused epilogue ----
    // SSM threads (wid 8..15) preload their constants during E1/E2.
    float cA = 0, cG = 0, cGf = 0, cGb = 0, cFo = 0, cfb = 0;
    int frame = 0, fch = 0;
    if (wid >= 8) {
        frame = (tid - 512) >> 5; fch = tid & 31;
        cGf = finW[fch]; cGb = finb[fch]; cFo = foutW[fch]; cfb = foutb[0];
    }
    // E2 waves preload Bs2 while E1 computes.
    bf16x8 Bx[2];
    int jt2 = wid - 4;
    if (wid >= 4 && wid < 8) {
        #pragma unroll
        for (int kc = 0; kc < 2; ++kc)
            Bx[kc] = ld_bfrag(s2sW, 2 * HF, jt2 * 16 + c, kc * 32 + quad * 8);
    }
    if (wid < 4) {   // E1: slow_feat = relu(h3[31]) @ soW + sob  (h3[31] in slot 1)
        bf16x8 a0 = ld_afrag(buf[3][1], c, quad, 0, true);
        bf16x8 a1 = ld_afrag(buf[3][1], c, quad, 1, true);
        bf16x8 Bso[2];
        #pragma unroll
        for (int kc = 0; kc < 2; ++kc)
            Bso[kc] = ld_bfrag(soW, GH, col, kc * 32 + quad * 8);
        float bv = sob[col];
        f32x4 accS = (f32x4){bv, bv, bv, bv};
        accS = MFMA16(a0, Bso[0], accS);
        accS = MFMA16(a1, Bso[1], accS);
        unsigned short* sf = buf[0][0];
        #pragma unroll
        for (int i = 0; i < 4; ++i) {
            int row = quad * 4 + i;
            int idx = (row << 6) + ((((col >> 3) ^ (row & 7))) << 3) + (col & 7);
            sf[idx] = (unsigned short)f2bf(accS[i]);
        }
    }
    __syncthreads();
    if (wid >= 4 && wid < 8) {   // E2: eps = sf @ s2sW + s2sb -> A_s | g_s
        bf16x8 s0 = ld_afrag(buf[0][0], c, quad, 0, false);
        bf16x8 s1 = ld_afrag(buf[0][0], c, quad, 1, false);
        int col2 = jt2 * 16 + c;
        float ev = s2sb[col2];
        f32x4 accE = (f32x4){ev, ev, ev, ev};
        accE = MFMA16(s0, Bx[0], accE);
        accE = MFMA16(s1, Bx[1], accE);
        #pragma unroll
        for (int i = 0; i < 4; ++i) {
            int row = quad * 4 + i;
            float v = accE[i];
            AG[row * 65 + col2] = (jt2 < 2) ? sigm(v) : v;
        }
    }
    __syncthreads();
    // E3: fast diagonal SSM + overlap-add. 16 frames x 32 ch on waves 8..15.
    if (wid >= 8) {
        int q = seqbase + frame;
        if (q < BS) {            // skip duplicated clamp frames (no double-add)
            int b  = (q >= ns) ? 1 : 0;
            int fi = q - b * ns;
            cA = AG[frame * 65 + fch];
            cG = AG[frame * 65 + 32 + fch];
            float Gf = cGf * cG;
            float Gb = cGb * cG;
            float h = 0.0f;
            float* op = out + (size_t)b * T + fi * DS;
            #pragma unroll 1
            for (int t = 0; t < LS; ++t) {
                float xv = xs[frame * 33 + t];
                h = fmaf(cA, h, fmaf(xv, Gf, Gb));
                float s = h * cFo;
                s += __shfl_xor(s, 1);
                s += __shfl_xor(s, 2);
                s += __shfl_xor(s, 4);
                s += __shfl_xor(s, 8);
                s += __shfl_xor(s, 16);
                if (fch == 0) atomicAdd(&op[t], s + cfb);
            }
        }
    }
}

extern "C" void kernel_launch(void* const* d_in, const int* in_sizes, int n_in,
                              void* d_out, int out_size, void* d_ws, size_t ws_size,
                              hipStream_t stream)
{
    (void)n_in; (void)ws_size; (void)d_ws;
    const float* x     = (const float*)d_in[0];
    const float* siW   = (const float*)d_in[1];
    const float* sib   = (const float*)d_in[2];
    const float* Wih   = (const float*)d_in[3];
    const float* Whh   = (const float*)d_in[4];
    const float* bih   = (const float*)d_in[5];
    const float* bhh   = (const float*)d_in[6];
    const float* soW   = (const float*)d_in[7];
    const float* sob   = (const float*)d_in[8];
    const float* s2sW  = (const float*)d_in[9];
    const float* s2sb  = (const float*)d_in[10];
    const float* finW  = (const float*)d_in[11];
    const float* finb  = (const float*)d_in[12];
    const float* foutW = (const float*)d_in[13];
    const float* foutb = (const float*)d_in[14];

    int T  = in_sizes[0] / 2;          // B = 2
    int ns = (T - LS) / DS + 1;        // 3999
    int BS = 2 * ns;                   // 7998

    (void)hipMemsetAsync(d_out, 0, (size_t)out_size * sizeof(float), stream);

    slowfast_fused<<<dim3((BS + 15) / 16), dim3(1024), 0, stream>>>(
        x, siW, sib, Wih, Whh, bih, bhh, soW, sob, s2sW, s2sb,
        finW, finb, foutW, foutb, (float*)d_out, T, ns, BS);
}